// Round 1
// baseline (2047.076 us; speedup 1.0000x reference)
//
#include <hip/hip_runtime.h>
#include <math.h>

#define B_ 4
#define N_ 1024
#define C_ 512
#define H_ 8
#define HD_ 64
#define SCALE_ 0.125f
#define LN_EPS_ 1e-5f

// ---------------------------------------------------------------------------
// Kernel 1: qkv = x @ Wqkv + bqkv
//   x: [4096, 512], Wqkv: [512, 1536], qkv: [4096, 1536]
//   64x64 tile, 16-wide K tile, 4x4 micro-tile per thread, 256 threads.
// ---------------------------------------------------------------------------
__global__ __launch_bounds__(256) void qkv_gemm(const float* __restrict__ x,
                                                const float* __restrict__ Wqkv,
                                                const float* __restrict__ bqkv,
                                                float* __restrict__ qkv) {
    const int M = B_ * N_;   // 4096
    const int K = C_;        // 512
    const int NN = 3 * C_;   // 1536
    __shared__ float As[64][17];   // +1 pad: rows stride 4 apart would alias banks at 16
    __shared__ float Bs[16][64];

    const int tid = threadIdx.x;
    const int tx = tid & 15;
    const int ty = tid >> 4;
    const int row0 = blockIdx.y * 64;
    const int col0 = blockIdx.x * 64;

    float acc[4][4] = {};

    for (int kt = 0; kt < K; kt += 16) {
        {   // A tile 64x16 (1024 floats, 4/thread via float4)
            int lin = tid * 4;
            int m = lin >> 4;
            int k = lin & 15;
            float4 a = *(const float4*)&x[(size_t)(row0 + m) * K + kt + k];
            As[m][k + 0] = a.x; As[m][k + 1] = a.y;
            As[m][k + 2] = a.z; As[m][k + 3] = a.w;
        }
        {   // B tile 16x64
            int lin = tid * 4;
            int kk = lin >> 6;
            int n = lin & 63;
            *(float4*)&Bs[kk][n] =
                *(const float4*)&Wqkv[(size_t)(kt + kk) * NN + col0 + n];
        }
        __syncthreads();
#pragma unroll
        for (int kk = 0; kk < 16; ++kk) {
            float a[4], bb[4];
#pragma unroll
            for (int i = 0; i < 4; ++i) a[i] = As[ty * 4 + i][kk];
#pragma unroll
            for (int j = 0; j < 4; ++j) bb[j] = Bs[kk][tx * 4 + j];
#pragma unroll
            for (int i = 0; i < 4; ++i)
#pragma unroll
                for (int j = 0; j < 4; ++j) acc[i][j] += a[i] * bb[j];
        }
        __syncthreads();
    }
#pragma unroll
    for (int i = 0; i < 4; ++i) {
        int r = row0 + ty * 4 + i;
        int c = col0 + tx * 4;
        float4 o;
        o.x = acc[i][0] + bqkv[c + 0];
        o.y = acc[i][1] + bqkv[c + 1];
        o.z = acc[i][2] + bqkv[c + 2];
        o.w = acc[i][3] + bqkv[c + 3];
        *(float4*)&qkv[(size_t)r * NN + c] = o;
    }
}

// ---------------------------------------------------------------------------
// Kernel 2: per (b,h,n) row: base = q.k^T*scale, polynomial, softmax,
//           write attn_final row, then ctx[b,n,h*64+d] = p @ v.
// qkv row layout: [3C] = [s=0..2][h][d];  q at +0, k at +C_, v at +2C_.
// ---------------------------------------------------------------------------
__global__ __launch_bounds__(256) void attn_kernel(const float* __restrict__ qkv,
                                                   const float* __restrict__ ow_in,
                                                   float* __restrict__ attn_out,
                                                   float* __restrict__ ctx) {
    __shared__ float qs[HD_];
    __shared__ float ps[N_];
    __shared__ float red[256];
    __shared__ float acc_s[4][HD_];

    const int idx = blockIdx.x;
    const int n = idx & (N_ - 1);
    const int h = (idx >> 10) & (H_ - 1);
    const int b = idx >> 13;
    const int tid = threadIdx.x;

    // softmax over the 3 order weights (redundant per-thread; trivial)
    float w0 = ow_in[0], w1 = ow_in[1], w2 = ow_in[2];
    float wm = fmaxf(w0, fmaxf(w1, w2));
    float e0 = __expf(w0 - wm), e1 = __expf(w1 - wm), e2 = __expf(w2 - wm);
    float einv = 1.0f / (e0 + e1 + e2);
    float ow0 = e0 * einv, ow1 = e1 * einv, ow2 = e2 * einv;

    const float* qrow = qkv + (size_t)(b * N_ + n) * (3 * C_) + h * HD_;
    if (tid < 16) ((float4*)qs)[tid] = ((const float4*)qrow)[tid];
    __syncthreads();

    float logit[4];
    float lmax = -1e30f;
#pragma unroll
    for (int c = 0; c < 4; ++c) {
        int j = tid + c * 256;
        const float4* krow =
            (const float4*)(qkv + (size_t)(b * N_ + j) * (3 * C_) + C_ + h * HD_);
        float s = 0.f;
#pragma unroll
        for (int d4 = 0; d4 < 16; ++d4) {
            float4 kv = krow[d4];
            float4 qv = ((const float4*)qs)[d4];
            s += qv.x * kv.x + qv.y * kv.y + qv.z * kv.z + qv.w * kv.w;
        }
        s *= SCALE_;
        float l = s * (ow0 + s * (ow1 + s * ow2));
        logit[c] = l;
        lmax = fmaxf(lmax, l);
    }

    red[tid] = lmax;
    __syncthreads();
    for (int s2 = 128; s2 > 0; s2 >>= 1) {
        if (tid < s2) red[tid] = fmaxf(red[tid], red[tid + s2]);
        __syncthreads();
    }
    float rowmax = red[0];
    __syncthreads();

    float pv[4];
    float lsum = 0.f;
#pragma unroll
    for (int c = 0; c < 4; ++c) {
        pv[c] = __expf(logit[c] - rowmax);
        lsum += pv[c];
    }
    red[tid] = lsum;
    __syncthreads();
    for (int s2 = 128; s2 > 0; s2 >>= 1) {
        if (tid < s2) red[tid] += red[tid + s2];
        __syncthreads();
    }
    float inv = 1.0f / red[0];

    float* orow = attn_out + (size_t)((b * H_ + h) * N_ + n) * N_;
#pragma unroll
    for (int c = 0; c < 4; ++c) {
        float p = pv[c] * inv;
        ps[tid + c * 256] = p;
        orow[tid + c * 256] = p;
    }
    __syncthreads();

    // PV: lane d in wave reads v coalesced (256B/wave/iter), p broadcast from LDS
    const int d = tid & 63;
    const int chunk = tid >> 6;
    const float* vbase = qkv + (size_t)(b * N_) * (3 * C_) + 2 * C_ + h * HD_ + d;
    float acc = 0.f;
    const int j0 = chunk * 256;
#pragma unroll 4
    for (int j = j0; j < j0 + 256; ++j) {
        acc += ps[j] * vbase[(size_t)j * (3 * C_)];
    }
    acc_s[chunk][d] = acc;
    __syncthreads();
    if (tid < 64) {
        float o = acc_s[0][tid] + acc_s[1][tid] + acc_s[2][tid] + acc_s[3][tid];
        ctx[(size_t)(b * N_ + n) * C_ + h * HD_ + tid] = o;
    }
}

// ---------------------------------------------------------------------------
// Kernel 3: per row (b,n): o = ctx_row @ Wproj + bproj; y = x + o; LayerNorm.
// ---------------------------------------------------------------------------
__global__ __launch_bounds__(256) void proj_ln(const float* __restrict__ ctx,
                                               const float* __restrict__ x,
                                               const float* __restrict__ Wproj,
                                               const float* __restrict__ bproj,
                                               const float* __restrict__ gamma,
                                               const float* __restrict__ beta,
                                               float* __restrict__ y) {
    __shared__ float rs[C_];
    __shared__ float red[256];
    const int row = blockIdx.x;
    const int tid = threadIdx.x;

    ((float2*)rs)[tid] = ((const float2*)(ctx + (size_t)row * C_))[tid];
    __syncthreads();

    float acc0 = bproj[tid];
    float acc1 = bproj[tid + 256];
#pragma unroll 8
    for (int k = 0; k < C_; ++k) {
        float a = rs[k];
        acc0 += a * Wproj[(size_t)k * C_ + tid];
        acc1 += a * Wproj[(size_t)k * C_ + tid + 256];
    }
    float y0 = acc0 + x[(size_t)row * C_ + tid];
    float y1 = acc1 + x[(size_t)row * C_ + tid + 256];

    red[tid] = y0 + y1;
    __syncthreads();
    for (int s2 = 128; s2 > 0; s2 >>= 1) {
        if (tid < s2) red[tid] += red[tid + s2];
        __syncthreads();
    }
    float mu = red[0] * (1.0f / C_);
    __syncthreads();
    float d0 = y0 - mu, d1 = y1 - mu;
    red[tid] = d0 * d0 + d1 * d1;
    __syncthreads();
    for (int s2 = 128; s2 > 0; s2 >>= 1) {
        if (tid < s2) red[tid] += red[tid + s2];
        __syncthreads();
    }
    float rstd = rsqrtf(red[0] * (1.0f / C_) + LN_EPS_);
    y[(size_t)row * C_ + tid]       = d0 * rstd * gamma[tid] + beta[tid];
    y[(size_t)row * C_ + tid + 256] = d1 * rstd * gamma[tid + 256] + beta[tid + 256];
}

extern "C" void kernel_launch(void* const* d_in, const int* in_sizes, int n_in,
                              void* d_out, int out_size, void* d_ws, size_t ws_size,
                              hipStream_t stream) {
    const float* x     = (const float*)d_in[0];
    const float* Wqkv  = (const float*)d_in[1];
    const float* bqkv  = (const float*)d_in[2];
    const float* ow    = (const float*)d_in[3];
    const float* Wproj = (const float*)d_in[4];
    const float* bproj = (const float*)d_in[5];
    const float* gamma = (const float*)d_in[6];
    const float* beta  = (const float*)d_in[7];

    float* out  = (float*)d_out;
    float* y    = out;                                  // [B,N,C]
    float* attn = out + (size_t)B_ * N_ * C_;           // [B,H,N,N]
    float* qkv  = (float*)d_ws;                         // [B*N, 3C]  25 MB
    float* ctx  = qkv + (size_t)B_ * N_ * 3 * C_;       // [B*N, C]    8 MB

    dim3 g1(3 * C_ / 64, B_ * N_ / 64);                 // (24, 64)
    qkv_gemm<<<g1, 256, 0, stream>>>(x, Wqkv, bqkv, qkv);
    attn_kernel<<<B_ * H_ * N_, 256, 0, stream>>>(qkv, ow, attn, ctx);
    proj_ln<<<B_ * N_, 256, 0, stream>>>(ctx, x, Wproj, bproj, gamma, beta, y);
}

// Round 2
// 557.642 us; speedup vs baseline: 3.6710x; 3.6710x over previous
//
#include <hip/hip_runtime.h>
#include <math.h>

#define B_ 4
#define N_ 1024
#define C_ 512
#define H_ 8
#define HD_ 64
#define SCALE_ 0.125f
#define LN_EPS_ 1e-5f

// ---------------------------------------------------------------------------
// Kernel 1: qkv = x @ Wqkv + bqkv   (unchanged from R1)
// ---------------------------------------------------------------------------
__global__ __launch_bounds__(256) void qkv_gemm(const float* __restrict__ x,
                                                const float* __restrict__ Wqkv,
                                                const float* __restrict__ bqkv,
                                                float* __restrict__ qkv) {
    const int K = C_;        // 512
    const int NN = 3 * C_;   // 1536
    __shared__ float As[64][17];
    __shared__ float Bs[16][64];

    const int tid = threadIdx.x;
    const int tx = tid & 15;
    const int ty = tid >> 4;
    const int row0 = blockIdx.y * 64;
    const int col0 = blockIdx.x * 64;

    float acc[4][4] = {};

    for (int kt = 0; kt < K; kt += 16) {
        {
            int lin = tid * 4;
            int m = lin >> 4;
            int k = lin & 15;
            float4 a = *(const float4*)&x[(size_t)(row0 + m) * K + kt + k];
            As[m][k + 0] = a.x; As[m][k + 1] = a.y;
            As[m][k + 2] = a.z; As[m][k + 3] = a.w;
        }
        {
            int lin = tid * 4;
            int kk = lin >> 6;
            int n = lin & 63;
            *(float4*)&Bs[kk][n] =
                *(const float4*)&Wqkv[(size_t)(kt + kk) * NN + col0 + n];
        }
        __syncthreads();
#pragma unroll
        for (int kk = 0; kk < 16; ++kk) {
            float a[4], bb[4];
#pragma unroll
            for (int i = 0; i < 4; ++i) a[i] = As[ty * 4 + i][kk];
#pragma unroll
            for (int j = 0; j < 4; ++j) bb[j] = Bs[kk][tx * 4 + j];
#pragma unroll
            for (int i = 0; i < 4; ++i)
#pragma unroll
                for (int j = 0; j < 4; ++j) acc[i][j] += a[i] * bb[j];
        }
        __syncthreads();
    }
#pragma unroll
    for (int i = 0; i < 4; ++i) {
        int r = row0 + ty * 4 + i;
        int c = col0 + tx * 4;
        float4 o;
        o.x = acc[i][0] + bqkv[c + 0];
        o.y = acc[i][1] + bqkv[c + 1];
        o.z = acc[i][2] + bqkv[c + 2];
        o.w = acc[i][3] + bqkv[c + 3];
        *(float4*)&qkv[(size_t)r * NN + c] = o;
    }
}

// ---------------------------------------------------------------------------
// Kernel 2: attn_scores — block = (b,h, 16 query rows), 256 threads (4 waves).
//   Wave ry owns rows ry*4..ry*4+3 entirely -> softmax via shfl only.
//   Scores kept in registers: s[4 col-tiles][4 rows x 4 cols] = 64/thread.
//   Q staged k-major (broadcast reads), K staged k-major (contig float4 reads).
// ---------------------------------------------------------------------------
__global__ __launch_bounds__(256) void attn_scores(const float* __restrict__ qkv,
                                                   const float* __restrict__ ow_in,
                                                   float* __restrict__ attn) {
    __shared__ __align__(16) float Qst[64][20];    // [k][row0..15]
    __shared__ __align__(16) float Kst[16][264];   // [k-chunk][col0..255]

    const int tid = threadIdx.x;
    const int lane = tid & 63;
    const int ry = tid >> 6;          // wave id 0..3
    const int n0 = blockIdx.x * 16;   // query-row tile
    const int bh = blockIdx.y;        // b*H + h
    const int b = bh >> 3, h = bh & 7;
    const size_t RS = 3 * C_;         // qkv row stride (floats)

    // softmax of the 3 order weights (tiny, per-thread)
    float w0 = ow_in[0], w1 = ow_in[1], w2 = ow_in[2];
    float wm = fmaxf(w0, fmaxf(w1, w2));
    float e0 = __expf(w0 - wm), e1 = __expf(w1 - wm), e2 = __expf(w2 - wm);
    float einv = 1.0f / (e0 + e1 + e2);
    float ow0 = e0 * einv, ow1 = e1 * einv, ow2 = e2 * einv;

    // stage Q tile (16 rows x 64 dims), k-major
    {
        int r = tid >> 4, f = tid & 15;
        const float* qrow = qkv + (size_t)(b * N_ + n0 + r) * RS + h * HD_;
        float4 qv = ((const float4*)qrow)[f];
        Qst[f * 4 + 0][r] = qv.x; Qst[f * 4 + 1][r] = qv.y;
        Qst[f * 4 + 2][r] = qv.z; Qst[f * 4 + 3][r] = qv.w;
    }

    float s[4][16];
    float lmax[4] = {-1e30f, -1e30f, -1e30f, -1e30f};

#pragma unroll
    for (int ct = 0; ct < 4; ++ct) {
#pragma unroll
        for (int u = 0; u < 16; ++u) s[ct][u] = 0.f;
#pragma unroll
        for (int kc = 0; kc < 4; ++kc) {
            // global loads first (latency overlap), then barrier, then LDS write
            const float* krow =
                qkv + (size_t)(b * N_ + ct * 256 + tid) * RS + C_ + h * HD_ + kc * 16;
            float4 kv0 = ((const float4*)krow)[0];
            float4 kv1 = ((const float4*)krow)[1];
            float4 kv2 = ((const float4*)krow)[2];
            float4 kv3 = ((const float4*)krow)[3];
            __syncthreads();
            Kst[ 0][tid] = kv0.x; Kst[ 1][tid] = kv0.y; Kst[ 2][tid] = kv0.z; Kst[ 3][tid] = kv0.w;
            Kst[ 4][tid] = kv1.x; Kst[ 5][tid] = kv1.y; Kst[ 6][tid] = kv1.z; Kst[ 7][tid] = kv1.w;
            Kst[ 8][tid] = kv2.x; Kst[ 9][tid] = kv2.y; Kst[10][tid] = kv2.z; Kst[11][tid] = kv2.w;
            Kst[12][tid] = kv3.x; Kst[13][tid] = kv3.y; Kst[14][tid] = kv3.z; Kst[15][tid] = kv3.w;
            __syncthreads();
#pragma unroll
            for (int kk = 0; kk < 16; ++kk) {
                float4 a4 = *(const float4*)&Qst[kc * 16 + kk][ry * 4];
                float4 b4 = *(const float4*)&Kst[kk][lane * 4];
                float a[4] = {a4.x, a4.y, a4.z, a4.w};
                float bb[4] = {b4.x, b4.y, b4.z, b4.w};
#pragma unroll
                for (int i = 0; i < 4; ++i)
#pragma unroll
                    for (int jj = 0; jj < 4; ++jj)
                        s[ct][i * 4 + jj] += a[i] * bb[jj];
            }
        }
        // scale + polynomial, track per-row local max
#pragma unroll
        for (int i = 0; i < 4; ++i)
#pragma unroll
            for (int jj = 0; jj < 4; ++jj) {
                float sc = s[ct][i * 4 + jj] * SCALE_;
                float l = sc * (ow0 + sc * (ow1 + sc * ow2));
                s[ct][i * 4 + jj] = l;
                lmax[i] = fmaxf(lmax[i], l);
            }
    }

    // row max across the wave (row fully owned by this wave)
#pragma unroll
    for (int i = 0; i < 4; ++i)
#pragma unroll
        for (int m = 1; m < 64; m <<= 1)
            lmax[i] = fmaxf(lmax[i], __shfl_xor(lmax[i], m, 64));

    float lsum[4] = {0.f, 0.f, 0.f, 0.f};
#pragma unroll
    for (int ct = 0; ct < 4; ++ct)
#pragma unroll
        for (int i = 0; i < 4; ++i)
#pragma unroll
            for (int jj = 0; jj < 4; ++jj) {
                float e = __expf(s[ct][i * 4 + jj] - lmax[i]);
                s[ct][i * 4 + jj] = e;
                lsum[i] += e;
            }
#pragma unroll
    for (int i = 0; i < 4; ++i)
#pragma unroll
        for (int m = 1; m < 64; m <<= 1)
            lsum[i] += __shfl_xor(lsum[i], m, 64);

    float inv[4];
#pragma unroll
    for (int i = 0; i < 4; ++i) inv[i] = 1.0f / lsum[i];

    // coalesced float4 writes of normalized probabilities
#pragma unroll
    for (int ct = 0; ct < 4; ++ct)
#pragma unroll
        for (int i = 0; i < 4; ++i) {
            float4 p;
            p.x = s[ct][i * 4 + 0] * inv[i];
            p.y = s[ct][i * 4 + 1] * inv[i];
            p.z = s[ct][i * 4 + 2] * inv[i];
            p.w = s[ct][i * 4 + 3] * inv[i];
            *(float4*)&attn[((size_t)bh * N_ + n0 + ry * 4 + i) * N_ + ct * 256 + lane * 4] = p;
        }
}

// ---------------------------------------------------------------------------
// Kernel 3: pv_gemm — per (b,h): ctx_tile[64n x 64d] = attn[64 x 1024] @ V[1024 x 64]
//   P staged transposed (m-major) so compute reads are broadcast float4s.
// ---------------------------------------------------------------------------
__global__ __launch_bounds__(256) void pv_gemm(const float* __restrict__ qkv,
                                               const float* __restrict__ attn,
                                               float* __restrict__ ctx) {
    __shared__ __align__(16) float Pst[64][68];   // [m][n]  (transposed P)
    __shared__ __align__(16) float Vs[64][68];    // [m][d]

    const int tid = threadIdx.x;
    const int tx = tid & 15;          // d-group
    const int ty = tid >> 4;          // n-group
    const int n0 = blockIdx.x * 64;
    const int bh = blockIdx.y;
    const int b = bh >> 3, h = bh & 7;
    const size_t RS = 3 * C_;

    const int rr = tid >> 2;          // staging row 0..63
    const int q = tid & 3;            // staging quarter

    float acc[4][4] = {};

    for (int mt = 0; mt < 16; ++mt) {
        const int m0 = mt * 64;
        const float* prow = attn + ((size_t)bh * N_ + n0 + rr) * N_ + m0 + q * 16;
        const float* vrow = qkv + (size_t)(b * N_ + m0 + rr) * RS + 2 * C_ + h * HD_ + q * 16;
        float4 pv[4], vv[4];
#pragma unroll
        for (int m = 0; m < 4; ++m) pv[m] = ((const float4*)prow)[m];
#pragma unroll
        for (int m = 0; m < 4; ++m) vv[m] = ((const float4*)vrow)[m];
        __syncthreads();
#pragma unroll
        for (int m = 0; m < 4; ++m) {
            int c = q * 16 + m * 4;
            Pst[c + 0][rr] = pv[m].x; Pst[c + 1][rr] = pv[m].y;
            Pst[c + 2][rr] = pv[m].z; Pst[c + 3][rr] = pv[m].w;
            *(float4*)&Vs[rr][c] = vv[m];
        }
        __syncthreads();
#pragma unroll 16
        for (int mm = 0; mm < 64; ++mm) {
            float4 a4 = *(const float4*)&Pst[mm][ty * 4];
            float4 b4 = *(const float4*)&Vs[mm][tx * 4];
            float a[4] = {a4.x, a4.y, a4.z, a4.w};
            float bb[4] = {b4.x, b4.y, b4.z, b4.w};
#pragma unroll
            for (int i = 0; i < 4; ++i)
#pragma unroll
                for (int j = 0; j < 4; ++j) acc[i][j] += a[i] * bb[j];
        }
    }
#pragma unroll
    for (int i = 0; i < 4; ++i) {
        float4 o;
        o.x = acc[i][0]; o.y = acc[i][1]; o.z = acc[i][2]; o.w = acc[i][3];
        *(float4*)&ctx[(size_t)(b * N_ + n0 + ty * 4 + i) * C_ + h * HD_ + tx * 4] = o;
    }
}

// ---------------------------------------------------------------------------
// Kernel 4: proj_ln (unchanged from R1)
// ---------------------------------------------------------------------------
__global__ __launch_bounds__(256) void proj_ln(const float* __restrict__ ctx,
                                               const float* __restrict__ x,
                                               const float* __restrict__ Wproj,
                                               const float* __restrict__ bproj,
                                               const float* __restrict__ gamma,
                                               const float* __restrict__ beta,
                                               float* __restrict__ y) {
    __shared__ float rs[C_];
    __shared__ float red[256];
    const int row = blockIdx.x;
    const int tid = threadIdx.x;

    ((float2*)rs)[tid] = ((const float2*)(ctx + (size_t)row * C_))[tid];
    __syncthreads();

    float acc0 = bproj[tid];
    float acc1 = bproj[tid + 256];
#pragma unroll 8
    for (int k = 0; k < C_; ++k) {
        float a = rs[k];
        acc0 += a * Wproj[(size_t)k * C_ + tid];
        acc1 += a * Wproj[(size_t)k * C_ + tid + 256];
    }
    float y0 = acc0 + x[(size_t)row * C_ + tid];
    float y1 = acc1 + x[(size_t)row * C_ + tid + 256];

    red[tid] = y0 + y1;
    __syncthreads();
    for (int s2 = 128; s2 > 0; s2 >>= 1) {
        if (tid < s2) red[tid] += red[tid + s2];
        __syncthreads();
    }
    float mu = red[0] * (1.0f / C_);
    __syncthreads();
    float d0 = y0 - mu, d1 = y1 - mu;
    red[tid] = d0 * d0 + d1 * d1;
    __syncthreads();
    for (int s2 = 128; s2 > 0; s2 >>= 1) {
        if (tid < s2) red[tid] += red[tid + s2];
        __syncthreads();
    }
    float rstd = rsqrtf(red[0] * (1.0f / C_) + LN_EPS_);
    y[(size_t)row * C_ + tid]       = d0 * rstd * gamma[tid] + beta[tid];
    y[(size_t)row * C_ + tid + 256] = d1 * rstd * gamma[tid + 256] + beta[tid + 256];
}

extern "C" void kernel_launch(void* const* d_in, const int* in_sizes, int n_in,
                              void* d_out, int out_size, void* d_ws, size_t ws_size,
                              hipStream_t stream) {
    const float* x     = (const float*)d_in[0];
    const float* Wqkv  = (const float*)d_in[1];
    const float* bqkv  = (const float*)d_in[2];
    const float* ow    = (const float*)d_in[3];
    const float* Wproj = (const float*)d_in[4];
    const float* bproj = (const float*)d_in[5];
    const float* gamma = (const float*)d_in[6];
    const float* beta  = (const float*)d_in[7];

    float* out  = (float*)d_out;
    float* y    = out;                                  // [B,N,C]
    float* attn = out + (size_t)B_ * N_ * C_;           // [B,H,N,N]
    float* qkv  = (float*)d_ws;                         // [B*N, 3C]  25 MB
    float* ctx  = qkv + (size_t)B_ * N_ * 3 * C_;       // [B*N, C]    8 MB

    dim3 g1(3 * C_ / 64, B_ * N_ / 64);                 // (24, 64)
    qkv_gemm<<<g1, 256, 0, stream>>>(x, Wqkv, bqkv, qkv);

    dim3 g2(N_ / 16, B_ * H_);                          // (64, 32)
    attn_scores<<<g2, 256, 0, stream>>>(qkv, ow, attn);

    dim3 g3(N_ / 64, B_ * H_);                          // (16, 32)
    pv_gemm<<<g3, 256, 0, stream>>>(qkv, attn, ctx);

    proj_ln<<<B_ * N_, 256, 0, stream>>>(ctx, x, Wproj, bproj, gamma, beta, y);
}

// Round 3
// 463.744 us; speedup vs baseline: 4.4142x; 1.2025x over previous
//
#include <hip/hip_runtime.h>
#include <math.h>

#define B_ 4
#define N_ 1024
#define C_ 512
#define H_ 8
#define HD_ 64
#define SCALE_ 0.125f
#define LN_EPS_ 1e-5f

// ---------------------------------------------------------------------------
// Kernel 1: qkv = x @ Wqkv + bqkv   (unchanged)
// ---------------------------------------------------------------------------
__global__ __launch_bounds__(256) void qkv_gemm(const float* __restrict__ x,
                                                const float* __restrict__ Wqkv,
                                                const float* __restrict__ bqkv,
                                                float* __restrict__ qkv) {
    const int K = C_;        // 512
    const int NN = 3 * C_;   // 1536
    __shared__ float As[64][17];
    __shared__ float Bs[16][64];

    const int tid = threadIdx.x;
    const int tx = tid & 15;
    const int ty = tid >> 4;
    const int row0 = blockIdx.y * 64;
    const int col0 = blockIdx.x * 64;

    float acc[4][4] = {};

    for (int kt = 0; kt < K; kt += 16) {
        {
            int lin = tid * 4;
            int m = lin >> 4;
            int k = lin & 15;
            float4 a = *(const float4*)&x[(size_t)(row0 + m) * K + kt + k];
            As[m][k + 0] = a.x; As[m][k + 1] = a.y;
            As[m][k + 2] = a.z; As[m][k + 3] = a.w;
        }
        {
            int lin = tid * 4;
            int kk = lin >> 6;
            int n = lin & 63;
            *(float4*)&Bs[kk][n] =
                *(const float4*)&Wqkv[(size_t)(kt + kk) * NN + col0 + n];
        }
        __syncthreads();
#pragma unroll
        for (int kk = 0; kk < 16; ++kk) {
            float a[4], bb[4];
#pragma unroll
            for (int i = 0; i < 4; ++i) a[i] = As[ty * 4 + i][kk];
#pragma unroll
            for (int j = 0; j < 4; ++j) bb[j] = Bs[kk][tx * 4 + j];
#pragma unroll
            for (int i = 0; i < 4; ++i)
#pragma unroll
                for (int j = 0; j < 4; ++j) acc[i][j] += a[i] * bb[j];
        }
        __syncthreads();
    }
#pragma unroll
    for (int i = 0; i < 4; ++i) {
        int r = row0 + ty * 4 + i;
        int c = col0 + tx * 4;
        float4 o;
        o.x = acc[i][0] + bqkv[c + 0];
        o.y = acc[i][1] + bqkv[c + 1];
        o.z = acc[i][2] + bqkv[c + 2];
        o.w = acc[i][3] + bqkv[c + 3];
        *(float4*)&qkv[(size_t)r * NN + c] = o;
    }
}

// ---------------------------------------------------------------------------
// Kernel 2: attn_scores (unchanged from R2)
// ---------------------------------------------------------------------------
__global__ __launch_bounds__(256) void attn_scores(const float* __restrict__ qkv,
                                                   const float* __restrict__ ow_in,
                                                   float* __restrict__ attn) {
    __shared__ __align__(16) float Qst[64][20];    // [k][row0..15]
    __shared__ __align__(16) float Kst[16][264];   // [k-chunk][col0..255]

    const int tid = threadIdx.x;
    const int lane = tid & 63;
    const int ry = tid >> 6;          // wave id 0..3
    const int n0 = blockIdx.x * 16;   // query-row tile
    const int bh = blockIdx.y;        // b*H + h
    const int b = bh >> 3, h = bh & 7;
    const size_t RS = 3 * C_;         // qkv row stride (floats)

    float w0 = ow_in[0], w1 = ow_in[1], w2 = ow_in[2];
    float wm = fmaxf(w0, fmaxf(w1, w2));
    float e0 = __expf(w0 - wm), e1 = __expf(w1 - wm), e2 = __expf(w2 - wm);
    float einv = 1.0f / (e0 + e1 + e2);
    float ow0 = e0 * einv, ow1 = e1 * einv, ow2 = e2 * einv;

    {
        int r = tid >> 4, f = tid & 15;
        const float* qrow = qkv + (size_t)(b * N_ + n0 + r) * RS + h * HD_;
        float4 qv = ((const float4*)qrow)[f];
        Qst[f * 4 + 0][r] = qv.x; Qst[f * 4 + 1][r] = qv.y;
        Qst[f * 4 + 2][r] = qv.z; Qst[f * 4 + 3][r] = qv.w;
    }

    float s[4][16];
    float lmax[4] = {-1e30f, -1e30f, -1e30f, -1e30f};

#pragma unroll
    for (int ct = 0; ct < 4; ++ct) {
#pragma unroll
        for (int u = 0; u < 16; ++u) s[ct][u] = 0.f;
#pragma unroll
        for (int kc = 0; kc < 4; ++kc) {
            const float* krow =
                qkv + (size_t)(b * N_ + ct * 256 + tid) * RS + C_ + h * HD_ + kc * 16;
            float4 kv0 = ((const float4*)krow)[0];
            float4 kv1 = ((const float4*)krow)[1];
            float4 kv2 = ((const float4*)krow)[2];
            float4 kv3 = ((const float4*)krow)[3];
            __syncthreads();
            Kst[ 0][tid] = kv0.x; Kst[ 1][tid] = kv0.y; Kst[ 2][tid] = kv0.z; Kst[ 3][tid] = kv0.w;
            Kst[ 4][tid] = kv1.x; Kst[ 5][tid] = kv1.y; Kst[ 6][tid] = kv1.z; Kst[ 7][tid] = kv1.w;
            Kst[ 8][tid] = kv2.x; Kst[ 9][tid] = kv2.y; Kst[10][tid] = kv2.z; Kst[11][tid] = kv2.w;
            Kst[12][tid] = kv3.x; Kst[13][tid] = kv3.y; Kst[14][tid] = kv3.z; Kst[15][tid] = kv3.w;
            __syncthreads();
#pragma unroll
            for (int kk = 0; kk < 16; ++kk) {
                float4 a4 = *(const float4*)&Qst[kc * 16 + kk][ry * 4];
                float4 b4 = *(const float4*)&Kst[kk][lane * 4];
                float a[4] = {a4.x, a4.y, a4.z, a4.w};
                float bb[4] = {b4.x, b4.y, b4.z, b4.w};
#pragma unroll
                for (int i = 0; i < 4; ++i)
#pragma unroll
                    for (int jj = 0; jj < 4; ++jj)
                        s[ct][i * 4 + jj] += a[i] * bb[jj];
            }
        }
#pragma unroll
        for (int i = 0; i < 4; ++i)
#pragma unroll
            for (int jj = 0; jj < 4; ++jj) {
                float sc = s[ct][i * 4 + jj] * SCALE_;
                float l = sc * (ow0 + sc * (ow1 + sc * ow2));
                s[ct][i * 4 + jj] = l;
                lmax[i] = fmaxf(lmax[i], l);
            }
    }

#pragma unroll
    for (int i = 0; i < 4; ++i)
#pragma unroll
        for (int m = 1; m < 64; m <<= 1)
            lmax[i] = fmaxf(lmax[i], __shfl_xor(lmax[i], m, 64));

    float lsum[4] = {0.f, 0.f, 0.f, 0.f};
#pragma unroll
    for (int ct = 0; ct < 4; ++ct)
#pragma unroll
        for (int i = 0; i < 4; ++i)
#pragma unroll
            for (int jj = 0; jj < 4; ++jj) {
                float e = __expf(s[ct][i * 4 + jj] - lmax[i]);
                s[ct][i * 4 + jj] = e;
                lsum[i] += e;
            }
#pragma unroll
    for (int i = 0; i < 4; ++i)
#pragma unroll
        for (int m = 1; m < 64; m <<= 1)
            lsum[i] += __shfl_xor(lsum[i], m, 64);

    float inv[4];
#pragma unroll
    for (int i = 0; i < 4; ++i) inv[i] = 1.0f / lsum[i];

#pragma unroll
    for (int ct = 0; ct < 4; ++ct)
#pragma unroll
        for (int i = 0; i < 4; ++i) {
            float4 p;
            p.x = s[ct][i * 4 + 0] * inv[i];
            p.y = s[ct][i * 4 + 1] * inv[i];
            p.z = s[ct][i * 4 + 2] * inv[i];
            p.w = s[ct][i * 4 + 3] * inv[i];
            *(float4*)&attn[((size_t)bh * N_ + n0 + ry * 4 + i) * N_ + ct * 256 + lane * 4] = p;
        }
}

// ---------------------------------------------------------------------------
// Kernel 3: pv_gemm (unchanged from R2)
// ---------------------------------------------------------------------------
__global__ __launch_bounds__(256) void pv_gemm(const float* __restrict__ qkv,
                                               const float* __restrict__ attn,
                                               float* __restrict__ ctx) {
    __shared__ __align__(16) float Pst[64][68];   // [m][n]  (transposed P)
    __shared__ __align__(16) float Vs[64][68];    // [m][d]

    const int tid = threadIdx.x;
    const int tx = tid & 15;          // d-group
    const int ty = tid >> 4;          // n-group
    const int n0 = blockIdx.x * 64;
    const int bh = blockIdx.y;
    const int b = bh >> 3, h = bh & 7;
    const size_t RS = 3 * C_;

    const int rr = tid >> 2;          // staging row 0..63
    const int q = tid & 3;            // staging quarter

    float acc[4][4] = {};

    for (int mt = 0; mt < 16; ++mt) {
        const int m0 = mt * 64;
        const float* prow = attn + ((size_t)bh * N_ + n0 + rr) * N_ + m0 + q * 16;
        const float* vrow = qkv + (size_t)(b * N_ + m0 + rr) * RS + 2 * C_ + h * HD_ + q * 16;
        float4 pv[4], vv[4];
#pragma unroll
        for (int m = 0; m < 4; ++m) pv[m] = ((const float4*)prow)[m];
#pragma unroll
        for (int m = 0; m < 4; ++m) vv[m] = ((const float4*)vrow)[m];
        __syncthreads();
#pragma unroll
        for (int m = 0; m < 4; ++m) {
            int c = q * 16 + m * 4;
            Pst[c + 0][rr] = pv[m].x; Pst[c + 1][rr] = pv[m].y;
            Pst[c + 2][rr] = pv[m].z; Pst[c + 3][rr] = pv[m].w;
            *(float4*)&Vs[rr][c] = vv[m];
        }
        __syncthreads();
#pragma unroll 16
        for (int mm = 0; mm < 64; ++mm) {
            float4 a4 = *(const float4*)&Pst[mm][ty * 4];
            float4 b4 = *(const float4*)&Vs[mm][tx * 4];
            float a[4] = {a4.x, a4.y, a4.z, a4.w};
            float bb[4] = {b4.x, b4.y, b4.z, b4.w};
#pragma unroll
            for (int i = 0; i < 4; ++i)
#pragma unroll
                for (int j = 0; j < 4; ++j) acc[i][j] += a[i] * bb[j];
        }
    }
#pragma unroll
    for (int i = 0; i < 4; ++i) {
        float4 o;
        o.x = acc[i][0]; o.y = acc[i][1]; o.z = acc[i][2]; o.w = acc[i][3];
        *(float4*)&ctx[(size_t)(b * N_ + n0 + ty * 4 + i) * C_ + h * HD_ + tx * 4] = o;
    }
}

// ---------------------------------------------------------------------------
// Kernel 4: proj_gemm — y_pre = ctx @ Wproj + bproj + x  (tiled GEMM, 64x64)
// ---------------------------------------------------------------------------
__global__ __launch_bounds__(256) void proj_gemm(const float* __restrict__ ctx,
                                                 const float* __restrict__ x,
                                                 const float* __restrict__ Wproj,
                                                 const float* __restrict__ bproj,
                                                 float* __restrict__ y) {
    const int K = C_;
    const int NN = C_;
    __shared__ float As[64][17];
    __shared__ float Bs[16][64];

    const int tid = threadIdx.x;
    const int tx = tid & 15;
    const int ty = tid >> 4;
    const int row0 = blockIdx.y * 64;
    const int col0 = blockIdx.x * 64;

    float acc[4][4] = {};

    for (int kt = 0; kt < K; kt += 16) {
        {
            int lin = tid * 4;
            int m = lin >> 4;
            int k = lin & 15;
            float4 a = *(const float4*)&ctx[(size_t)(row0 + m) * K + kt + k];
            As[m][k + 0] = a.x; As[m][k + 1] = a.y;
            As[m][k + 2] = a.z; As[m][k + 3] = a.w;
        }
        {
            int lin = tid * 4;
            int kk = lin >> 6;
            int n = lin & 63;
            *(float4*)&Bs[kk][n] =
                *(const float4*)&Wproj[(size_t)(kt + kk) * NN + col0 + n];
        }
        __syncthreads();
#pragma unroll
        for (int kk = 0; kk < 16; ++kk) {
            float a[4], bb[4];
#pragma unroll
            for (int i = 0; i < 4; ++i) a[i] = As[ty * 4 + i][kk];
#pragma unroll
            for (int j = 0; j < 4; ++j) bb[j] = Bs[kk][tx * 4 + j];
#pragma unroll
            for (int i = 0; i < 4; ++i)
#pragma unroll
                for (int j = 0; j < 4; ++j) acc[i][j] += a[i] * bb[j];
        }
        __syncthreads();
    }
#pragma unroll
    for (int i = 0; i < 4; ++i) {
        int r = row0 + ty * 4 + i;
        int c = col0 + tx * 4;
        float4 xr = *(const float4*)&x[(size_t)r * C_ + c];
        float4 o;
        o.x = acc[i][0] + bproj[c + 0] + xr.x;
        o.y = acc[i][1] + bproj[c + 1] + xr.y;
        o.z = acc[i][2] + bproj[c + 2] + xr.z;
        o.w = acc[i][3] + bproj[c + 3] + xr.w;
        *(float4*)&y[(size_t)r * C_ + c] = o;
    }
}

// ---------------------------------------------------------------------------
// Kernel 5: ln_kernel — in-place LayerNorm over each 512-wide row of y.
//   One block (4 waves) per row; single-pass sum/sumsq via shfl + LDS combine.
// ---------------------------------------------------------------------------
__global__ __launch_bounds__(256) void ln_kernel(float* __restrict__ y,
                                                 const float* __restrict__ gamma,
                                                 const float* __restrict__ beta) {
    __shared__ float wsum[4], wsq[4];
    const int row = blockIdx.x;
    const int tid = threadIdx.x;
    const int lane = tid & 63;
    const int w = tid >> 6;

    float2 v = ((const float2*)(y + (size_t)row * C_))[tid];
    float s = v.x + v.y;
    float sq = v.x * v.x + v.y * v.y;
#pragma unroll
    for (int m = 1; m < 64; m <<= 1) {
        s += __shfl_xor(s, m, 64);
        sq += __shfl_xor(sq, m, 64);
    }
    if (lane == 0) { wsum[w] = s; wsq[w] = sq; }
    __syncthreads();
    float ts = wsum[0] + wsum[1] + wsum[2] + wsum[3];
    float tq = wsq[0] + wsq[1] + wsq[2] + wsq[3];
    float mu = ts * (1.0f / C_);
    float var = tq * (1.0f / C_) - mu * mu;
    float rstd = rsqrtf(var + LN_EPS_);

    float2 g = ((const float2*)gamma)[tid];
    float2 be = ((const float2*)beta)[tid];
    float2 o;
    o.x = (v.x - mu) * rstd * g.x + be.x;
    o.y = (v.y - mu) * rstd * g.y + be.y;
    ((float2*)(y + (size_t)row * C_))[tid] = o;
}

extern "C" void kernel_launch(void* const* d_in, const int* in_sizes, int n_in,
                              void* d_out, int out_size, void* d_ws, size_t ws_size,
                              hipStream_t stream) {
    const float* x     = (const float*)d_in[0];
    const float* Wqkv  = (const float*)d_in[1];
    const float* bqkv  = (const float*)d_in[2];
    const float* ow    = (const float*)d_in[3];
    const float* Wproj = (const float*)d_in[4];
    const float* bproj = (const float*)d_in[5];
    const float* gamma = (const float*)d_in[6];
    const float* beta  = (const float*)d_in[7];

    float* out  = (float*)d_out;
    float* y    = out;                                  // [B,N,C]
    float* attn = out + (size_t)B_ * N_ * C_;           // [B,H,N,N]
    float* qkv  = (float*)d_ws;                         // [B*N, 3C]  25 MB
    float* ctx  = qkv + (size_t)B_ * N_ * 3 * C_;       // [B*N, C]    8 MB

    dim3 g1(3 * C_ / 64, B_ * N_ / 64);                 // (24, 64)
    qkv_gemm<<<g1, 256, 0, stream>>>(x, Wqkv, bqkv, qkv);

    dim3 g2(N_ / 16, B_ * H_);                          // (64, 32)
    attn_scores<<<g2, 256, 0, stream>>>(qkv, ow, attn);

    dim3 g3(N_ / 64, B_ * H_);                          // (16, 32)
    pv_gemm<<<g3, 256, 0, stream>>>(qkv, attn, ctx);

    dim3 g4(C_ / 64, B_ * N_ / 64);                     // (8, 64)
    proj_gemm<<<g4, 256, 0, stream>>>(ctx, x, Wproj, bproj, y);

    ln_kernel<<<B_ * N_, 256, 0, stream>>>(y, gamma, beta);
}